// Round 2
// baseline (388.588 us; speedup 1.0000x reference)
//
#include <hip/hip_runtime.h>
#include <math.h>

#define EMB 128

// ---------------------------------------------------------------------------
// Kernel 0: segment starts. batch_idx is sorted; start[b] = lower_bound(b).
// Writes every element of start[0..nb] exactly once per call (ws is re-poisoned
// before every timed launch, so we must fully rewrite it each call).
// ---------------------------------------------------------------------------
__global__ void seg_start_kernel(const int* __restrict__ bidx,
                                 int* __restrict__ start, int n, int nb) {
    int i = blockIdx.x * blockDim.x + threadIdx.x;
    if (i >= n) return;
    int bi = bidx[i];
    int bp = (i == 0) ? -1 : bidx[i - 1];
    for (int b = bp + 1; b <= bi; ++b) start[b] = i;
    if (i == n - 1) {
        for (int b = bi + 1; b <= nb; ++b) start[b] = n;
    }
}

// ---------------------------------------------------------------------------
// Main kernel: one block (256 threads = 4 waves = 8 half-waves) per graph.
// Phase 1: online-softmax weighted x-sum over the segment (single x pass).
// Phase 2: tiny per-graph matmuls  g = t@Wv+bv ; h = [g,gp]@Wm+bm ;
//          out = gp + leaky_relu(h).
// ---------------------------------------------------------------------------
__launch_bounds__(256, 4)
__global__ void pool_kernel(const float* __restrict__ x,
                            const float* __restrict__ g_prev,
                            const int* __restrict__ seg_start,
                            const float* __restrict__ Wg,
                            const float* __restrict__ bg,
                            const float* __restrict__ Wv,
                            const float* __restrict__ bv,
                            const float* __restrict__ Wm,
                            const float* __restrict__ bm,
                            float* __restrict__ out) {
    const int b    = blockIdx.x;
    const int tid  = threadIdx.x;
    const int lane = tid & 63;
    const int warp = tid >> 6;
    const int half = lane >> 5;
    const int sub  = lane & 31;
    const int h    = warp * 2 + half;   // half-wave index 0..7

    __shared__ float sh_m[8];
    __shared__ float sh_d[8];
    __shared__ float sh_s[8][128];
    __shared__ float sh_t[128];
    __shared__ float sh_g[128];
    __shared__ float sh_gp[128];
    __shared__ int   sh_se[2];

    if (tid == 0) { sh_se[0] = seg_start[b]; sh_se[1] = seg_start[b + 1]; }
    __syncthreads();
    const int start = sh_se[0];
    const int end   = sh_se[1];

    // Per-lane Wg fragment (elements 4*sub .. 4*sub+3) and bias.
    float4 wg  = *reinterpret_cast<const float4*>(Wg + 4 * sub);
    float  bg0 = bg[0];

    // Online softmax state, maintained redundantly across the 32-lane half.
    float  m = -INFINITY;
    float  d = 0.0f;
    float4 s = make_float4(0.f, 0.f, 0.f, 0.f);

    int r = start + h;
    float4 xc = make_float4(0.f, 0.f, 0.f, 0.f);
    if (r < end)
        xc = *reinterpret_cast<const float4*>(x + (size_t)r * EMB + 4 * sub);

    for (; r < end; r += 8) {
        // prefetch next row for this half-wave
        float4 xn = make_float4(0.f, 0.f, 0.f, 0.f);
        int rn = r + 8;
        if (rn < end)
            xn = *reinterpret_cast<const float4*>(x + (size_t)rn * EMB + 4 * sub);

        // gate = x_row . Wg  (butterfly reduce within the 32-lane half)
        float p = xc.x * wg.x + xc.y * wg.y + xc.z * wg.z + xc.w * wg.w;
        #pragma unroll
        for (int off = 16; off >= 1; off >>= 1) p += __shfl_xor(p, off);
        float gate = p + bg0;

        // branchless online-softmax update
        float mnew = fmaxf(m, gate);
        float corr = __expf(m - mnew);      // exp(-inf) = 0 on first row
        float e    = __expf(gate - mnew);
        d   = d * corr + e;
        s.x = s.x * corr + e * xc.x;
        s.y = s.y * corr + e * xc.y;
        s.z = s.z * corr + e * xc.z;
        s.w = s.w * corr + e * xc.w;
        m   = mnew;
        xc  = xn;
    }

    // ---- merge the 8 half-wave states in LDS ----
    *reinterpret_cast<float4*>(&sh_s[h][4 * sub]) = s;
    if (sub == 0) { sh_m[h] = m; sh_d[h] = d; }
    __syncthreads();

    if (tid < 128) {
        float M = -INFINITY;
        #pragma unroll
        for (int i = 0; i < 8; ++i) M = fmaxf(M, sh_m[i]);
        float ts = 0.f, ds = 0.f;
        #pragma unroll
        for (int i = 0; i < 8; ++i) {
            float mi = sh_m[i];
            float w  = (mi == -INFINITY) ? 0.0f : __expf(mi - M);
            ts += w * sh_s[i][tid];
            ds += w * sh_d[i];
        }
        // non-empty segment => ds >= 1 (the max-attaining row contributes 1)
        sh_t[tid] = (start < end) ? (ts / ds) : 0.0f;
    }
    __syncthreads();

    // ---- phase 2: g = t @ Wv + bv  (empty segment => g = 0 exactly) ----
    if (tid < 128) {
        float acc = 0.0f;
        if (start < end) {
            acc = bv[tid];
            for (int k = 0; k < 128; ++k)
                acc += sh_t[k] * Wv[k * 128 + tid];   // coalesced across tid
        }
        sh_g[tid]  = acc;
        sh_gp[tid] = g_prev[(size_t)b * EMB + tid];
    }
    __syncthreads();

    // ---- h = [g, gp] @ Wm + bm ; out = gp + leaky_relu(h) ----
    if (tid < 128) {
        float hacc = bm[tid];
        for (int k = 0; k < 128; ++k)
            hacc += sh_g[k] * Wm[k * 128 + tid];
        for (int k = 0; k < 128; ++k)
            hacc += sh_gp[k] * Wm[(128 + k) * 128 + tid];
        float gp = sh_gp[tid];
        out[(size_t)b * EMB + tid] = gp + (hacc > 0.f ? hacc : 0.01f * hacc);
    }
}

extern "C" void kernel_launch(void* const* d_in, const int* in_sizes, int n_in,
                              void* d_out, int out_size, void* d_ws, size_t ws_size,
                              hipStream_t stream) {
    const float* x      = (const float*)d_in[0];
    const float* g_prev = (const float*)d_in[1];
    const int*   bidx   = (const int*)d_in[2];
    const float* Wg     = (const float*)d_in[3];
    const float* bg     = (const float*)d_in[4];
    const float* Wv     = (const float*)d_in[5];
    const float* bv     = (const float*)d_in[6];
    const float* Wm     = (const float*)d_in[7];
    const float* bm     = (const float*)d_in[8];
    float* out = (float*)d_out;

    const int N = in_sizes[0] / EMB;          // 524288
    const int B = in_sizes[1] / EMB;          // 1024

    int* seg_start = (int*)d_ws;              // (B+1) ints

    seg_start_kernel<<<(N + 255) / 256, 256, 0, stream>>>(bidx, seg_start, N, B);
    pool_kernel<<<B, 256, 0, stream>>>(x, g_prev, seg_start,
                                       Wg, bg, Wv, bv, Wm, bm, out);
}

// Round 4
// 387.249 us; speedup vs baseline: 1.0035x; 1.0035x over previous
//
#include <hip/hip_runtime.h>
#include <math.h>

#define EMB 128

// ---------------------------------------------------------------------------
// Kernel 0: segment starts. batch_idx is sorted; start[b] = lower_bound(b).
// Fully rewrites start[0..nb] every call (ws is re-poisoned before each launch).
// ---------------------------------------------------------------------------
__global__ void seg_start_kernel(const int* __restrict__ bidx,
                                 int* __restrict__ start, int n, int nb) {
    int i = blockIdx.x * blockDim.x + threadIdx.x;
    if (i >= n) return;
    int bi = bidx[i];
    int bp = (i == 0) ? -1 : bidx[i - 1];
    for (int b = bp + 1; b <= bi; ++b) start[b] = i;
    if (i == n - 1) {
        for (int b = bi + 1; b <= nb; ++b) start[b] = n;
    }
}

// ---------------------------------------------------------------------------
// Main kernel: one block (256 threads = 4 waves = 8 half-waves) per graph.
// Phase 1: online-softmax weighted x-sum, 4 rows per half-wave per iteration
//          (32 contiguous rows per block-iteration; 4 loads in flight and 4
//          independent butterfly chains per half-wave for latency hiding).
// Phase 2: tiny per-graph matmuls, k-split across all 256 threads.
// ---------------------------------------------------------------------------
__launch_bounds__(256, 4)
__global__ void pool_kernel(const float* __restrict__ x,
                            const float* __restrict__ g_prev,
                            const int* __restrict__ seg_start,
                            const float* __restrict__ Wg,
                            const float* __restrict__ bg,
                            const float* __restrict__ Wv,
                            const float* __restrict__ bv,
                            const float* __restrict__ Wm,
                            const float* __restrict__ bm,
                            float* __restrict__ out) {
    const int b    = blockIdx.x;
    const int tid  = threadIdx.x;
    const int lane = tid & 63;
    const int warp = tid >> 6;
    const int half = lane >> 5;
    const int sub  = lane & 31;
    const int h    = warp * 2 + half;   // half-wave index 0..7

    __shared__ float sh_m[8];
    __shared__ float sh_d[8];
    __shared__ float sh_s[8][128];
    __shared__ float sh_t[128];
    __shared__ float sh_g[128];
    __shared__ float sh_gp[128];
    __shared__ float sh_p[2][128];
    __shared__ int   sh_se[2];

    if (tid == 0) { sh_se[0] = seg_start[b]; sh_se[1] = seg_start[b + 1]; }
    __syncthreads();
    const int start = sh_se[0];
    const int end   = sh_se[1];

    // Per-lane Wg fragment (elements 4*sub .. 4*sub+3) and bias.
    float4 wg  = *reinterpret_cast<const float4*>(Wg + 4 * sub);
    float  bg0 = bg[0];

    // Online softmax state (redundant across the 32-lane half).
    float  m = -INFINITY;
    float  d = 0.0f;
    float4 s = make_float4(0.f, 0.f, 0.f, 0.f);

    const float4 zero4 = make_float4(0.f, 0.f, 0.f, 0.f);

    // Half-wave h owns rows start + h*4 + 32*iter + {0,1,2,3}.
    int r0 = start + h * 4;
    float4 xc0 = zero4, xc1 = zero4, xc2 = zero4, xc3 = zero4;
    if (r0 + 0 < end) xc0 = *reinterpret_cast<const float4*>(x + (size_t)(r0 + 0) * EMB + 4 * sub);
    if (r0 + 1 < end) xc1 = *reinterpret_cast<const float4*>(x + (size_t)(r0 + 1) * EMB + 4 * sub);
    if (r0 + 2 < end) xc2 = *reinterpret_cast<const float4*>(x + (size_t)(r0 + 2) * EMB + 4 * sub);
    if (r0 + 3 < end) xc3 = *reinterpret_cast<const float4*>(x + (size_t)(r0 + 3) * EMB + 4 * sub);

    for (; r0 < end; ) {
        const int rn = r0 + 32;
        // prefetch next batch (4 loads in flight during the compute chain)
        float4 xn0 = zero4, xn1 = zero4, xn2 = zero4, xn3 = zero4;
        if (rn < end) {
            xn0 = *reinterpret_cast<const float4*>(x + (size_t)(rn + 0) * EMB + 4 * sub);
            if (rn + 1 < end) xn1 = *reinterpret_cast<const float4*>(x + (size_t)(rn + 1) * EMB + 4 * sub);
            if (rn + 2 < end) xn2 = *reinterpret_cast<const float4*>(x + (size_t)(rn + 2) * EMB + 4 * sub);
            if (rn + 3 < end) xn3 = *reinterpret_cast<const float4*>(x + (size_t)(rn + 3) * EMB + 4 * sub);
        }

        // 4 per-row partial dots
        float p0 = xc0.x * wg.x + xc0.y * wg.y + xc0.z * wg.z + xc0.w * wg.w;
        float p1 = xc1.x * wg.x + xc1.y * wg.y + xc1.z * wg.z + xc1.w * wg.w;
        float p2 = xc2.x * wg.x + xc2.y * wg.y + xc2.z * wg.z + xc2.w * wg.w;
        float p3 = xc3.x * wg.x + xc3.y * wg.y + xc3.z * wg.z + xc3.w * wg.w;

        // 4 independent butterfly chains, interleaved for ILP
        #pragma unroll
        for (int off = 16; off >= 1; off >>= 1) {
            p0 += __shfl_xor(p0, off);
            p1 += __shfl_xor(p1, off);
            p2 += __shfl_xor(p2, off);
            p3 += __shfl_xor(p3, off);
        }

        // invalid rows -> gate = -inf -> e = 0   (r0 itself is always valid here)
        float g0 = p0 + bg0;                                  // r0 < end guaranteed
        float g1 = (r0 + 1 < end) ? (p1 + bg0) : -INFINITY;
        float g2 = (r0 + 2 < end) ? (p2 + bg0) : -INFINITY;
        float g3 = (r0 + 3 < end) ? (p3 + bg0) : -INFINITY;

        // one softmax correction per 4 rows
        float mb   = fmaxf(fmaxf(g0, g1), fmaxf(g2, g3));
        float mnew = fmaxf(m, mb);                             // finite (g0 finite)
        float corr = __expf(m - mnew);                         // exp(-inf)=0 first time
        float e0 = __expf(g0 - mnew);
        float e1 = __expf(g1 - mnew);
        float e2 = __expf(g2 - mnew);
        float e3 = __expf(g3 - mnew);

        d   = d * corr + (e0 + e1 + e2 + e3);
        s.x = s.x * corr + e0 * xc0.x + e1 * xc1.x + e2 * xc2.x + e3 * xc3.x;
        s.y = s.y * corr + e0 * xc0.y + e1 * xc1.y + e2 * xc2.y + e3 * xc3.y;
        s.z = s.z * corr + e0 * xc0.z + e1 * xc1.z + e2 * xc2.z + e3 * xc3.z;
        s.w = s.w * corr + e0 * xc0.w + e1 * xc1.w + e2 * xc2.w + e3 * xc3.w;
        m   = mnew;

        xc0 = xn0; xc1 = xn1; xc2 = xn2; xc3 = xn3;
        r0  = rn;
    }

    // ---- merge the 8 half-wave states in LDS ----
    *reinterpret_cast<float4*>(&sh_s[h][4 * sub]) = s;
    if (sub == 0) { sh_m[h] = m; sh_d[h] = d; }
    __syncthreads();

    if (tid < 128) {
        float M = -INFINITY;
        #pragma unroll
        for (int i = 0; i < 8; ++i) M = fmaxf(M, sh_m[i]);
        float ts = 0.f, ds = 0.f;
        #pragma unroll
        for (int i = 0; i < 8; ++i) {
            float mi = sh_m[i];
            float w  = (mi == -INFINITY) ? 0.0f : __expf(mi - M);
            ts += w * sh_s[i][tid];
            ds += w * sh_d[i];
        }
        sh_t[tid]  = (start < end) ? (ts / ds) : 0.0f;   // non-empty => ds >= 1
        sh_gp[tid] = g_prev[(size_t)b * EMB + tid];
    }
    __syncthreads();

    // ---- phase 2: g = t @ Wv + bv, k-split across 256 threads ----
    {
        const int col = tid & 127;
        const int kh  = tid >> 7;                 // 0 or 1
        float acc = 0.0f;
        #pragma unroll 4
        for (int k = kh * 64; k < kh * 64 + 64; ++k)
            acc += sh_t[k] * Wv[k * 128 + col];   // coalesced across col
        sh_p[kh][col] = acc;
    }
    __syncthreads();
    if (tid < 128) {
        sh_g[tid] = (start < end) ? (sh_p[0][tid] + sh_p[1][tid] + bv[tid]) : 0.0f;
    }
    __syncthreads();

    // ---- h = [g, gp] @ Wm + bm, k-split across 256 threads ----
    {
        const int col = tid & 127;
        const int kh  = tid >> 7;                 // 0: g-rows, 1: gp-rows
        const float* src = (kh == 0) ? sh_g : sh_gp;
        const float* wmp = Wm + (size_t)kh * 128 * 128;
        float acc = 0.0f;
        #pragma unroll 4
        for (int k = 0; k < 128; ++k)
            acc += src[k] * wmp[k * 128 + col];
        sh_p[kh][col] = acc;
    }
    __syncthreads();
    if (tid < 128) {
        float hacc = sh_p[0][tid] + sh_p[1][tid] + bm[tid];
        float gp   = sh_gp[tid];
        out[(size_t)b * EMB + tid] = gp + (hacc > 0.f ? hacc : 0.01f * hacc);
    }
}

extern "C" void kernel_launch(void* const* d_in, const int* in_sizes, int n_in,
                              void* d_out, int out_size, void* d_ws, size_t ws_size,
                              hipStream_t stream) {
    const float* x      = (const float*)d_in[0];
    const float* g_prev = (const float*)d_in[1];
    const int*   bidx   = (const int*)d_in[2];
    const float* Wg     = (const float*)d_in[3];
    const float* bg     = (const float*)d_in[4];
    const float* Wv     = (const float*)d_in[5];
    const float* bv     = (const float*)d_in[6];
    const float* Wm     = (const float*)d_in[7];
    const float* bm     = (const float*)d_in[8];
    float* out = (float*)d_out;

    const int N = in_sizes[0] / EMB;          // 524288
    const int B = in_sizes[1] / EMB;          // 1024

    int* seg_start = (int*)d_ws;              // (B+1) ints

    seg_start_kernel<<<(N + 255) / 256, 256, 0, stream>>>(bidx, seg_start, N, B);
    pool_kernel<<<B, 256, 0, stream>>>(x, g_prev, seg_start,
                                       Wg, bg, Wv, bv, Wm, bm, out);
}